// Round 4
// baseline (117.274 us; speedup 1.0000x reference)
//
#include <hip/hip_runtime.h>
#include <hip/hip_bf16.h>

#define NNODES 100000
#define NEDGES 1600000
#define IN_C   256
#define OUT_C  128

typedef short bf16x8 __attribute__((ext_vector_type(8)));
typedef float f32x4  __attribute__((ext_vector_type(4)));

static __device__ __forceinline__ unsigned short f2bf(float f) {
    union { float f; unsigned u; } c; c.f = f;
    unsigned r = c.u + 0x7fffu + ((c.u >> 16) & 1u);   // round-to-nearest-even
    return (unsigned short)(r >> 16);
}
static __device__ __forceinline__ float bflo(unsigned u) {
    union { unsigned u; float f; } c; c.u = u << 16; return c.f;
}
static __device__ __forceinline__ float bfhi(unsigned u) {
    union { unsigned u; float f; } c; c.u = u & 0xffff0000u; return c.f;
}

union BF8 { bf16x8 v; unsigned short s[8]; };

// ---------------------------------------------------------------------------
// GEMM: H(bf16) = X @ W^T.  X:[N,256] f32, W:[128,256] f32.
// M-tile 64, full K=256 staged once (32 KB LDS). 512 threads = 8 waves;
// wave wid owns output cols wid*16..wid*16+15 with its W fragments (all 8
// k-slices) held in VGPRs (converted once from L2-resident W). Forced
// VGPR<=128 -> 16 waves/CU. XOR-swizzled LDS: ds_read_b128 ~2-way (free).
// ---------------------------------------------------------------------------
__global__ __launch_bounds__(512, 4) void gemm_xwt(const float* __restrict__ X,
                                                   const float* __restrict__ W,
                                                   unsigned short* __restrict__ H) {
    __shared__ unsigned short Xs[64 * 256];   // bf16 bits, swizzled, 32 KB

    const int tid  = threadIdx.x;
    const int lane = tid & 63;
    const int wid  = tid >> 6;            // 0..7 -> n-frag (cols wid*16..+15)
    const int row0 = blockIdx.x * 64;
    const int wr   = lane & 15;           // row/col within fragment
    const int ko   = (lane >> 4) * 8;     // k sub-offset within 32-slice

    // --- W fragments in VGPRs: 8 k-slices of this wave's 16 output cols ---
    bf16x8 wf[8];
#pragma unroll
    for (int ks = 0; ks < 8; ++ks) {
        const float* src = W + (size_t)(wid * 16 + wr) * IN_C + ks * 32 + ko;
        float4 a = *(const float4*)src;
        float4 b = *(const float4*)(src + 4);
        BF8 t;
        t.s[0] = f2bf(a.x); t.s[1] = f2bf(a.y); t.s[2] = f2bf(a.z); t.s[3] = f2bf(a.w);
        t.s[4] = f2bf(b.x); t.s[5] = f2bf(b.y); t.s[6] = f2bf(b.z); t.s[7] = f2bf(b.w);
        wf[ks] = t.v;
    }

    // --- stage X tile: 64 rows x 256 k, f32 -> bf16, one phase ---
#pragma unroll
    for (int p = 0; p < 8; ++p) {
        int idx = p * 512 + tid;          // 0..4095 ; wave covers one row/iter
        int r   = idx >> 6;               // 0..63
        int c4  = idx & 63;               // float4 column
        float4 v = make_float4(0.f, 0.f, 0.f, 0.f);
        if (row0 + r < NNODES)
            v = *(const float4*)(X + (size_t)(row0 + r) * IN_C + c4 * 4);
        int byte = (r * 512 + c4 * 8) ^ ((r & 7) << 4);
        *(ushort4*)((char*)Xs + byte) =
            make_ushort4(f2bf(v.x), f2bf(v.y), f2bf(v.z), f2bf(v.w));
    }
    __syncthreads();

    // --- compute: 4 m-frags x 8 k-slices = 32 MFMAs, 4 independent chains ---
    f32x4 acc[4] = {};
#pragma unroll
    for (int ks = 0; ks < 8; ++ks) {
        const int kb = ks * 64 + (lane >> 4) * 16;   // byte offset within row
#pragma unroll
        for (int m = 0; m < 4; ++m) {
            int r    = m * 16 + wr;
            int byte = (r * 512 + kb) ^ ((r & 7) << 4);
            bf16x8 a = *(const bf16x8*)((const char*)Xs + byte);
            acc[m] = __builtin_amdgcn_mfma_f32_16x16x32_bf16(a, wf[ks], acc[m],
                                                             0, 0, 0);
        }
    }

    // --- epilogue: C/D layout col=lane&15, row=(lane>>4)*4+reg ---
#pragma unroll
    for (int m = 0; m < 4; ++m) {
#pragma unroll
        for (int r = 0; r < 4; ++r) {
            int grow = row0 + m * 16 + (lane >> 4) * 4 + r;
            if (grow < NNODES)
                H[(size_t)grow * OUT_C + wid * 16 + wr] = f2bf(acc[m][r]);
        }
    }
}

// ---------------------------------------------------------------------------
// rowptr[r] = lower_bound(A_rows, r)  (A_rows sorted).  r in [0, N].
// ---------------------------------------------------------------------------
__global__ __launch_bounds__(256) void build_rowptr(const int* __restrict__ rows,
                                                    int* __restrict__ rowptr) {
    int r = blockIdx.x * 256 + threadIdx.x;
    if (r > NNODES) return;
    int lo = 0, hi = NEDGES;
    while (lo < hi) {
        int mid = (lo + hi) >> 1;
        if (rows[mid] < r) lo = mid + 1; else hi = mid;
    }
    rowptr[r] = lo;
}

// ---------------------------------------------------------------------------
// SpMM: out[r,:] = sum_e vals[e] * H[cols[e],:].  One wave per row.
// 16 lanes per edge (uint4 = 8 bf16 ch/lane), 4 edges per load instruction,
// 16-edge unroll -> 4 dwordx4 gathers in flight. cols/vals preloaded per
// 64-edge chunk, broadcast via shfl. Final shfl_xor(16/32) reduction.
// ---------------------------------------------------------------------------
__global__ __launch_bounds__(256) void spmm_rows(const uint4* __restrict__ H4,
                                                 const int* __restrict__ rowptr,
                                                 const int* __restrict__ cols,
                                                 const float* __restrict__ vals,
                                                 float* __restrict__ out) {
    const int wid  = threadIdx.x >> 6;
    const int lane = threadIdx.x & 63;
    const int row  = blockIdx.x * 4 + wid;
    if (row >= NNODES) return;

    const int s  = rowptr[row];
    const int e  = rowptr[row + 1];
    const int g  = lane >> 4;      // edge subgroup 0..3
    const int cg = lane & 15;      // channel group: channels cg*8 .. cg*8+7

    float acc[8];
#pragma unroll
    for (int t = 0; t < 8; ++t) acc[t] = 0.f;

    for (int base = s; base < e; base += 64) {
        const int cnt = (e - base < 64) ? (e - base) : 64;
        int   ec = 0;
        float ev = 0.f;
        if (lane < cnt) { ec = cols[base + lane]; ev = vals[base + lane]; }

        int j = 0;
        // main: 16 edges per iteration -> 4 independent 16B gathers in flight
        for (; j + 16 <= cnt; j += 16) {
#pragma unroll
            for (int q = 0; q < 4; ++q) {
                int   c = __shfl(ec, j + q * 4 + g);
                float v = __shfl(ev, j + q * 4 + g);
                uint4 u = H4[(size_t)c * 16 + cg];
                acc[0] += v * bflo(u.x); acc[1] += v * bfhi(u.x);
                acc[2] += v * bflo(u.y); acc[3] += v * bfhi(u.y);
                acc[4] += v * bflo(u.z); acc[5] += v * bfhi(u.z);
                acc[6] += v * bflo(u.w); acc[7] += v * bfhi(u.w);
            }
        }
        // tail: 4 edges at a time (overshoot lanes have ev=0 -> contribute 0)
        for (; j < cnt; j += 4) {
            int   c = __shfl(ec, j + g);
            float v = __shfl(ev, j + g);
            uint4 u = H4[(size_t)c * 16 + cg];
            acc[0] += v * bflo(u.x); acc[1] += v * bfhi(u.x);
            acc[2] += v * bflo(u.y); acc[3] += v * bfhi(u.y);
            acc[4] += v * bflo(u.z); acc[5] += v * bfhi(u.z);
            acc[6] += v * bflo(u.w); acc[7] += v * bfhi(u.w);
        }
    }

    // reduce across the 4 edge subgroups (lanes cg, cg+16, cg+32, cg+48)
#pragma unroll
    for (int t = 0; t < 8; ++t) {
        acc[t] += __shfl_xor(acc[t], 16);
        acc[t] += __shfl_xor(acc[t], 32);
    }
    if (lane < 16) {
        float4 v0 = make_float4(acc[0], acc[1], acc[2], acc[3]);
        float4 v1 = make_float4(acc[4], acc[5], acc[6], acc[7]);
        *(float4*)(out + (size_t)row * OUT_C + cg * 8)     = v0;
        *(float4*)(out + (size_t)row * OUT_C + cg * 8 + 4) = v1;
    }
}

// ---------------------------------------------------------------------------
extern "C" void kernel_launch(void* const* d_in, const int* in_sizes, int n_in,
                              void* d_out, int out_size, void* d_ws, size_t ws_size,
                              hipStream_t stream) {
    const float* X      = (const float*)d_in[0];
    const float* W      = (const float*)d_in[1];
    const int*   A_rows = (const int*)d_in[2];
    const int*   A_cols = (const int*)d_in[3];
    const float* A_vals = (const float*)d_in[4];
    float* out = (float*)d_out;

    unsigned short* H   = (unsigned short*)d_ws;                    // 25.6 MB bf16
    int* rowptr = (int*)((char*)d_ws +
                         (size_t)NNODES * OUT_C * sizeof(unsigned short));

    gemm_xwt<<<(NNODES + 63) / 64, 512, 0, stream>>>(X, W, H);
    build_rowptr<<<(NNODES + 1 + 255) / 256, 256, 0, stream>>>(A_rows, rowptr);
    spmm_rows<<<(NNODES + 3) / 4, 256, 0, stream>>>((const uint4*)H, rowptr,
                                                    A_cols, A_vals, out);
}

// Round 5
// 101.523 us; speedup vs baseline: 1.1551x; 1.1551x over previous
//
#include <hip/hip_runtime.h>
#include <hip/hip_bf16.h>

#define NNODES 100000
#define NEDGES 1600000
#define IN_C   256
#define OUT_C  128

typedef short bf16x8 __attribute__((ext_vector_type(8)));
typedef float f32x4  __attribute__((ext_vector_type(4)));

static __device__ __forceinline__ unsigned short f2bf(float f) {
    union { float f; unsigned u; } c; c.f = f;
    unsigned r = c.u + 0x7fffu + ((c.u >> 16) & 1u);   // round-to-nearest-even
    return (unsigned short)(r >> 16);
}
static __device__ __forceinline__ float bflo(unsigned u) {
    union { unsigned u; float f; } c; c.u = u << 16; return c.f;
}
static __device__ __forceinline__ float bfhi(unsigned u) {
    union { unsigned u; float f; } c; c.u = u & 0xffff0000u; return c.f;
}

union BF8 { bf16x8 v; unsigned short s[8]; };

// ---------------------------------------------------------------------------
// GEMM: H(bf16) = X @ W^T.  X:[N,256] f32, W:[128,256] f32.
// Structure: W (131KB, L2-resident) staged ONCE per block into 64KB
// XOR-swizzled LDS (bf16). X is loaded DIRECTLY from global into MFMA
// A-fragments (no LDS, no K-loop barrier): lane l covers row r0+(l&15),
// k-bytes (l>>4)*16 -> per instruction 16 fully-consumed 128B segments.
// 512 threads = 8 waves; wave owns 16 rows x all 128 cols:
// 8 acc chains x 8 k-slices = 64 MFMAs, barrier-free K-loop.
// ---------------------------------------------------------------------------
__global__ __launch_bounds__(512, 4) void gemm_xwt(const float* __restrict__ X,
                                                   const float* __restrict__ W,
                                                   unsigned short* __restrict__ H) {
    __shared__ unsigned short Wsh[128 * 256];   // bf16 bits, [n][k], swizzled, 64KB

    const int tid  = threadIdx.x;
    const int lane = tid & 63;
    const int wid  = tid >> 6;                  // 0..7

    // --- stage W once: 128 n x 256 k, f32 -> bf16, 16 float4 per thread ---
#pragma unroll
    for (int p = 0; p < 16; ++p) {
        int idx = p * 512 + tid;                // 0..8191 float4 index
        int n   = idx >> 6;                     // 0..127
        int c4  = idx & 63;                     // float4 column
        float4 v = *(const float4*)(W + (size_t)n * IN_C + c4 * 4);
        int byte = (n * 512 + c4 * 8) ^ ((n & 7) << 4);
        *(ushort4*)((char*)Wsh + byte) =
            make_ushort4(f2bf(v.x), f2bf(v.y), f2bf(v.z), f2bf(v.w));
    }
    __syncthreads();

    // --- this wave's 16 rows; lane reads its own A-fragment slice ---
    const int r0   = blockIdx.x * 128 + wid * 16;
    int arow = r0 + (lane & 15);
    if (arow > NNODES - 1) arow = NNODES - 1;   // clamp (tail rows discarded)
    const float* xrow = X + (size_t)arow * IN_C + (lane >> 4) * 8;

    f32x4 acc[8] = {};
#pragma unroll
    for (int ks = 0; ks < 8; ++ks) {
        float4 a0 = *(const float4*)(xrow + ks * 32);
        float4 a1 = *(const float4*)(xrow + ks * 32 + 4);
        BF8 t;
        t.s[0] = f2bf(a0.x); t.s[1] = f2bf(a0.y); t.s[2] = f2bf(a0.z); t.s[3] = f2bf(a0.w);
        t.s[4] = f2bf(a1.x); t.s[5] = f2bf(a1.y); t.s[6] = f2bf(a1.z); t.s[7] = f2bf(a1.w);
        const int kb = ks * 64 + (lane >> 4) * 16;      // byte offset in W row
#pragma unroll
        for (int n8 = 0; n8 < 8; ++n8) {
            int nr   = n8 * 16 + (lane & 15);
            int byte = (nr * 512 + kb) ^ ((nr & 7) << 4);
            bf16x8 b = *(const bf16x8*)((const char*)Wsh + byte);
            acc[n8] = __builtin_amdgcn_mfma_f32_16x16x32_bf16(t.v, b, acc[n8],
                                                              0, 0, 0);
        }
    }

    // --- epilogue: C/D layout col=lane&15, row=(lane>>4)*4+reg ---
#pragma unroll
    for (int n8 = 0; n8 < 8; ++n8) {
#pragma unroll
        for (int r = 0; r < 4; ++r) {
            int grow = r0 + (lane >> 4) * 4 + r;
            if (grow < NNODES)
                H[(size_t)grow * OUT_C + n8 * 16 + (lane & 15)] = f2bf(acc[n8][r]);
        }
    }
}

// ---------------------------------------------------------------------------
// rowptr[r] = lower_bound(A_rows, r)  (A_rows sorted).  r in [0, N].
// ---------------------------------------------------------------------------
__global__ __launch_bounds__(256) void build_rowptr(const int* __restrict__ rows,
                                                    int* __restrict__ rowptr) {
    int r = blockIdx.x * 256 + threadIdx.x;
    if (r > NNODES) return;
    int lo = 0, hi = NEDGES;
    while (lo < hi) {
        int mid = (lo + hi) >> 1;
        if (rows[mid] < r) lo = mid + 1; else hi = mid;
    }
    rowptr[r] = lo;
}

// ---------------------------------------------------------------------------
// SpMM: out[r,:] = sum_e vals[e] * H[cols[e],:].  One wave per row.
// 16 lanes per edge (uint4 = 8 bf16 ch/lane), 4 edges per load instruction,
// 16-edge unroll -> 4 dwordx4 gathers in flight. cols/vals preloaded per
// 64-edge chunk, broadcast via shfl. Final shfl_xor(16/32) reduction.
// ---------------------------------------------------------------------------
__global__ __launch_bounds__(256) void spmm_rows(const uint4* __restrict__ H4,
                                                 const int* __restrict__ rowptr,
                                                 const int* __restrict__ cols,
                                                 const float* __restrict__ vals,
                                                 float* __restrict__ out) {
    const int wid  = threadIdx.x >> 6;
    const int lane = threadIdx.x & 63;
    const int row  = blockIdx.x * 4 + wid;
    if (row >= NNODES) return;

    const int s  = rowptr[row];
    const int e  = rowptr[row + 1];
    const int g  = lane >> 4;      // edge subgroup 0..3
    const int cg = lane & 15;      // channel group: channels cg*8 .. cg*8+7

    float acc[8];
#pragma unroll
    for (int t = 0; t < 8; ++t) acc[t] = 0.f;

    for (int base = s; base < e; base += 64) {
        const int cnt = (e - base < 64) ? (e - base) : 64;
        int   ec = 0;
        float ev = 0.f;
        if (lane < cnt) { ec = cols[base + lane]; ev = vals[base + lane]; }

        int j = 0;
        // main: 16 edges per iteration -> 4 independent 16B gathers in flight
        for (; j + 16 <= cnt; j += 16) {
#pragma unroll
            for (int q = 0; q < 4; ++q) {
                int   c = __shfl(ec, j + q * 4 + g);
                float v = __shfl(ev, j + q * 4 + g);
                uint4 u = H4[(size_t)c * 16 + cg];
                acc[0] += v * bflo(u.x); acc[1] += v * bfhi(u.x);
                acc[2] += v * bflo(u.y); acc[3] += v * bfhi(u.y);
                acc[4] += v * bflo(u.z); acc[5] += v * bfhi(u.z);
                acc[6] += v * bflo(u.w); acc[7] += v * bfhi(u.w);
            }
        }
        // tail: 4 edges at a time (overshoot lanes have ev=0 -> contribute 0)
        for (; j < cnt; j += 4) {
            int   c = __shfl(ec, j + g);
            float v = __shfl(ev, j + g);
            uint4 u = H4[(size_t)c * 16 + cg];
            acc[0] += v * bflo(u.x); acc[1] += v * bfhi(u.x);
            acc[2] += v * bflo(u.y); acc[3] += v * bfhi(u.y);
            acc[4] += v * bflo(u.z); acc[5] += v * bfhi(u.z);
            acc[6] += v * bflo(u.w); acc[7] += v * bfhi(u.w);
        }
    }

    // reduce across the 4 edge subgroups (lanes cg, cg+16, cg+32, cg+48)
#pragma unroll
    for (int t = 0; t < 8; ++t) {
        acc[t] += __shfl_xor(acc[t], 16);
        acc[t] += __shfl_xor(acc[t], 32);
    }
    if (lane < 16) {
        float4 v0 = make_float4(acc[0], acc[1], acc[2], acc[3]);
        float4 v1 = make_float4(acc[4], acc[5], acc[6], acc[7]);
        *(float4*)(out + (size_t)row * OUT_C + cg * 8)     = v0;
        *(float4*)(out + (size_t)row * OUT_C + cg * 8 + 4) = v1;
    }
}

// ---------------------------------------------------------------------------
extern "C" void kernel_launch(void* const* d_in, const int* in_sizes, int n_in,
                              void* d_out, int out_size, void* d_ws, size_t ws_size,
                              hipStream_t stream) {
    const float* X      = (const float*)d_in[0];
    const float* W      = (const float*)d_in[1];
    const int*   A_rows = (const int*)d_in[2];
    const int*   A_cols = (const int*)d_in[3];
    const float* A_vals = (const float*)d_in[4];
    float* out = (float*)d_out;

    unsigned short* H   = (unsigned short*)d_ws;                    // 25.6 MB bf16
    int* rowptr = (int*)((char*)d_ws +
                         (size_t)NNODES * OUT_C * sizeof(unsigned short));

    gemm_xwt<<<(NNODES + 127) / 128, 512, 0, stream>>>(X, W, H);
    build_rowptr<<<(NNODES + 1 + 255) / 256, 256, 0, stream>>>(A_rows, rowptr);
    spmm_rows<<<(NNODES + 3) / 4, 256, 0, stream>>>((const uint4*)H, rowptr,
                                                    A_cols, A_vals, out);
}